// Round 1
// 6302.970 us; speedup vs baseline: 1.4073x; 1.4073x over previous
//
#include <hip/hip_runtime.h>
#include <math.h>

#define T_ 100
#define B_ 64
#define S_ 128
#define E_ 512
#define H_ 1024
#define C_ 512
#define V_ 32000
#define TS_ 99            // T-1 steps
#define R_ (TS_ * B_)     // 6336 rows
#define MP_ 6400          // rows padded to multiple of 128 for MFMA
#define NT2 250           // vocab n-tiles of 128

typedef unsigned short ushort_t;
typedef __attribute__((ext_vector_type(8))) short short8;
typedef __attribute__((ext_vector_type(4))) float f32x4;

__device__ __forceinline__ float sigm_(float x) { return 1.0f / (1.0f + __expf(-x)); }
__device__ __forceinline__ float tanh_(float x) { float e = __expf(2.0f * x); return 1.0f - 2.0f / (e + 1.0f); }
__device__ __forceinline__ ushort_t f2bf(float f) {
    unsigned u = __float_as_uint(f);
    unsigned r = (u + 0x7FFF + ((u >> 16) & 1)) >> 16;
    return (ushort_t)r;
}
__device__ __forceinline__ float bf2f(ushort_t u) { return __uint_as_float(((unsigned)u) << 16); }

__device__ __forceinline__ float wred(float v) {
    #pragma unroll
    for (int o = 32; o; o >>= 1) v += __shfl_down(v, o);
    return v;
}
__device__ __forceinline__ float wmax(float v) {
    #pragma unroll
    for (int o = 32; o; o >>= 1) v = fmaxf(v, __shfl_down(v, o));
    return v;
}

// ---------------------------------------------------------------------------
// bf16 MFMA partial GEMM-NT for the per-step recurrent GEMMs.
// Output P[ks][64][N] (fp32 partial sums), K split into slices of 256.
// Slices ks < s0 come from (A0, W0, lda0); ks >= s0 from (A1, W1, lda1).
// If A1 == nullptr and ks >= s0, the slice is written as zeros (t==0 case).
// Block: 256 thr (4 waves); block computes 64 rows x 64 cols for its slice.
// ---------------------------------------------------------------------------
__global__ __launch_bounds__(256) void mfma_partial(
    const ushort_t* __restrict__ A0, int lda0, const ushort_t* __restrict__ W0,
    const ushort_t* __restrict__ A1, int lda1, const ushort_t* __restrict__ W1,
    int s0, float* __restrict__ P, int N) {
    __shared__ ushort_t As[64 * 72];
    __shared__ ushort_t Bs[64 * 72];
    const int tid = threadIdx.x;
    const int n0 = blockIdx.x * 64, ks = blockIdx.y;
    const int w = tid >> 6, lane = tid & 63;
    const int quad = lane >> 4, l16 = lane & 15;
    f32x4 acc[4] = {};
    const ushort_t* Ap = nullptr;
    const ushort_t* Wp = nullptr;
    int lda = 0;
    bool zero = false;
    if (ks < s0) {
        int k0 = ks * 256;
        Ap = A0 + k0; Wp = W0 + k0; lda = lda0;
    } else if (A1) {
        int k0 = (ks - s0) * 256;
        Ap = A1 + k0; Wp = W1 + k0; lda = lda1;
    } else {
        zero = true;
    }
    if (!zero) {
        for (int kc = 0; kc < 256; kc += 64) {
            __syncthreads();
            #pragma unroll
            for (int i = 0; i < 2; ++i) {
                int cid = i * 256 + tid;
                int row = cid >> 3, c8 = cid & 7;
                *(uint4*)(&As[row * 72 + c8 * 8]) = *(const uint4*)(Ap + (size_t)row * lda + kc + c8 * 8);
                *(uint4*)(&Bs[row * 72 + c8 * 8]) = *(const uint4*)(Wp + (size_t)(n0 + row) * lda + kc + c8 * 8);
            }
            __syncthreads();
            #pragma unroll
            for (int ks2 = 0; ks2 < 2; ++ks2) {
                short8 bfrag = *(const short8*)(&Bs[(w * 16 + l16) * 72 + ks2 * 32 + quad * 8]);
                #pragma unroll
                for (int i = 0; i < 4; ++i) {
                    short8 afrag = *(const short8*)(&As[(i * 16 + l16) * 72 + ks2 * 32 + quad * 8]);
                    acc[i] = __builtin_amdgcn_mfma_f32_16x16x32_bf16(afrag, bfrag, acc[i], 0, 0, 0);
                }
            }
        }
    }
    const int col = n0 + w * 16 + l16;
    #pragma unroll
    for (int i = 0; i < 4; ++i)
        #pragma unroll
        for (int r = 0; r < 4; ++r)
            P[((size_t)ks * 64 + i * 16 + quad * 4 + r) * N + col] = acc[i][r];
}

// GRU gate combine: sums 6 partial slices (0..1 x-source, 2..5 h-source) +
// biases -> gates -> h_out written fp32 AND bf16. 256 blk x 256 thr.
__global__ __launch_bounds__(256) void gru_gate(const float* __restrict__ P,
                                                const float* __restrict__ bi,
                                                const float* __restrict__ bh,
                                                const float* __restrict__ hp,
                                                float* __restrict__ hf,
                                                ushort_t* __restrict__ hbf) {
    const int idx = blockIdx.x * 256 + threadIdx.x;
    const int b = idx >> 10, j = idx & 1023;
    float ir = bi[j], iz = bi[1024 + j], in_ = bi[2048 + j];
    float hr = bh[j], hz = bh[1024 + j], hn = bh[2048 + j];
    #pragma unroll
    for (int ks = 0; ks < 2; ++ks) {
        const float* q = P + ((size_t)ks * 64 + b) * 3072;
        ir += q[j]; iz += q[1024 + j]; in_ += q[2048 + j];
    }
    #pragma unroll
    for (int ks = 2; ks < 6; ++ks) {
        const float* q = P + ((size_t)ks * 64 + b) * 3072;
        hr += q[j]; hz += q[1024 + j]; hn += q[2048 + j];
    }
    float hprev = hp ? hp[(size_t)b * 1024 + j] : 0.0f;
    float r = sigm_(ir + hr);
    float z = sigm_(iz + hz);
    float n = tanh_(in_ + r * hn);
    float h = (1.0f - z) * n + z * hprev;
    hf[(size_t)b * 1024 + j] = h;
    hbf[(size_t)b * 1024 + j] = f2bf(h);
}

// attention: sums hid partials (4 slices), scores -> softmax over S -> z.
// All ctx reads in bf16. Writes z fp32 + bf16. grid = B_, block 256.
__global__ __launch_bounds__(256) void attn_step(const ushort_t* __restrict__ ctxp_bf,
                                                 const ushort_t* __restrict__ ctx_bf,
                                                 const float* __restrict__ Ph,
                                                 const float* __restrict__ wmlp,
                                                 float* __restrict__ zf,
                                                 ushort_t* __restrict__ zbf) {
    __shared__ __align__(16) float hd[512];
    __shared__ __align__(16) float wm[512];
    __shared__ float sc[128];
    const int b = blockIdx.x;
    const int tid = threadIdx.x;
    for (int k = tid; k < 512; k += 256) {
        float s = 0;
        #pragma unroll
        for (int p = 0; p < 4; ++p) s += Ph[((size_t)p * 64 + b) * 512 + k];
        hd[k] = s;
        wm[k] = wmlp[k];
    }
    __syncthreads();
    const int wave = tid >> 6, lane = tid & 63;
    for (int s = wave; s < 128; s += 4) {
        const ushort_t* cp = ctxp_bf + ((size_t)s * B_ + b) * 512 + lane * 8;
        short8 v = *(const short8*)cp;
        float acc = 0;
        #pragma unroll
        for (int k = 0; k < 8; ++k) {
            int c = lane * 8 + k;
            acc += tanh_(bf2f((ushort_t)v[k]) + hd[c]) * wm[c];
        }
        acc = wred(acc);
        if (lane == 0) sc[s] = acc;
    }
    __syncthreads();
    if (wave == 0) {
        float s0 = sc[lane], s1 = sc[lane + 64];
        float m = fmaxf(s0, s1);
        m = wmax(m); m = __shfl(m, 0);
        float e0 = __expf(s0 - m), e1 = __expf(s1 - m);
        float ssum = wred(e0 + e1); ssum = __shfl(ssum, 0);
        float inv = 1.0f / ssum;
        sc[lane] = e0 * inv; sc[lane + 64] = e1 * inv;
    }
    __syncthreads();
    {
        const int c = tid * 2;
        float a0 = 0, a1 = 0;
        #pragma unroll 8
        for (int s = 0; s < 128; ++s) {
            ushort2 u = *(const ushort2*)(ctx_bf + ((size_t)s * B_ + b) * 512 + c);
            float w_ = sc[s];
            a0 = fmaf(w_, bf2f(u.x), a0);
            a1 = fmaf(w_, bf2f(u.y), a1);
        }
        zf[(size_t)b * 512 + c] = a0;
        zf[(size_t)b * 512 + c + 1] = a1;
        *(ushort2*)(zbf + (size_t)b * 512 + c) = make_ushort2(f2bf(a0), f2bf(a1));
    }
}

// ---------------------------------------------------------------------------
// bf16 MFMA GEMM-NT, 128x128 tile, K-chunk 64 via LDS (padded stride 72).
// EPI==0: plain store acc+bias -> fp32 C.  EPI==1: tanh(acc+bias) -> fp32 C
// and bf16 C2.  EPI==2: fused per-row online-LSE partials -> pp.
// ---------------------------------------------------------------------------
template <int EPI>
__global__ __launch_bounds__(256) void mfma_nt(const ushort_t* __restrict__ A,
                                               const ushort_t* __restrict__ Bw,
                                               const float* __restrict__ bias,
                                               float* __restrict__ Cf,
                                               ushort_t* __restrict__ Cbf,
                                               float2* __restrict__ pp,
                                               int N, int K, int NT) {
    __shared__ ushort_t As[128 * 72];
    __shared__ ushort_t Bs[128 * 72];
    __shared__ float smM[2][128], smS[2][128];
    const int tid = threadIdx.x;
    const int m0 = blockIdx.y * 128, n0 = blockIdx.x * 128;
    const int w = tid >> 6, lane = tid & 63;
    const int quad = lane >> 4, l16 = lane & 15;
    f32x4 acc[4][4] = {};
    for (int kc = 0; kc < K; kc += 64) {
        __syncthreads();
        #pragma unroll
        for (int i = 0; i < 4; ++i) {
            int cid = i * 256 + tid;
            int row = cid >> 3, c8 = cid & 7;
            uint4 va = *(const uint4*)(A + (size_t)(m0 + row) * K + kc + c8 * 8);
            *(uint4*)(&As[row * 72 + c8 * 8]) = va;
            uint4 vb = *(const uint4*)(Bw + (size_t)(n0 + row) * K + kc + c8 * 8);
            *(uint4*)(&Bs[row * 72 + c8 * 8]) = vb;
        }
        __syncthreads();
        #pragma unroll
        for (int ks = 0; ks < 2; ++ks) {
            short8 af[4], bfr[4];
            #pragma unroll
            for (int i = 0; i < 4; ++i)
                af[i] = *(const short8*)(&As[((w >> 1) * 64 + i * 16 + l16) * 72 + ks * 32 + quad * 8]);
            #pragma unroll
            for (int j = 0; j < 4; ++j)
                bfr[j] = *(const short8*)(&Bs[((w & 1) * 64 + j * 16 + l16) * 72 + ks * 32 + quad * 8]);
            #pragma unroll
            for (int i = 0; i < 4; ++i)
                #pragma unroll
                for (int j = 0; j < 4; ++j)
                    acc[i][j] = __builtin_amdgcn_mfma_f32_16x16x32_bf16(af[i], bfr[j], acc[i][j], 0, 0, 0);
        }
    }
    const int colbase = n0 + (w & 1) * 64;
    const int rowbase = m0 + (w >> 1) * 64;
    if (EPI == 0) {
        #pragma unroll
        for (int j = 0; j < 4; ++j) {
            int col = colbase + j * 16 + l16;
            float bv = bias ? bias[col] : 0.0f;
            #pragma unroll
            for (int i = 0; i < 4; ++i) {
                #pragma unroll
                for (int r = 0; r < 4; ++r) {
                    int row = rowbase + i * 16 + quad * 4 + r;
                    Cf[(size_t)row * N + col] = acc[i][j][r] + bv;
                }
            }
        }
    } else if (EPI == 1) {
        #pragma unroll
        for (int j = 0; j < 4; ++j) {
            int col = colbase + j * 16 + l16;
            float bv = bias[col];
            #pragma unroll
            for (int i = 0; i < 4; ++i) {
                #pragma unroll
                for (int r = 0; r < 4; ++r) {
                    int row = rowbase + i * 16 + quad * 4 + r;
                    float v = tanh_(acc[i][j][r] + bv);
                    Cf[(size_t)row * N + col] = v;
                    Cbf[(size_t)row * N + col] = f2bf(v);
                }
            }
        }
    } else {  // EPI == 2: LSE partials
        float bv[4];
        #pragma unroll
        for (int j = 0; j < 4; ++j) bv[j] = bias[colbase + j * 16 + l16];
        #pragma unroll
        for (int i = 0; i < 4; ++i) {
            #pragma unroll
            for (int r = 0; r < 4; ++r) {
                float x0 = acc[i][0][r] + bv[0], x1 = acc[i][1][r] + bv[1];
                float x2 = acc[i][2][r] + bv[2], x3 = acc[i][3][r] + bv[3];
                float mx = fmaxf(fmaxf(x0, x1), fmaxf(x2, x3));
                #pragma unroll
                for (int o = 1; o < 16; o <<= 1) mx = fmaxf(mx, __shfl_xor(mx, o));
                float s = __expf(x0 - mx) + __expf(x1 - mx) + __expf(x2 - mx) + __expf(x3 - mx);
                #pragma unroll
                for (int o = 1; o < 16; o <<= 1) s += __shfl_xor(s, o);
                if (l16 == 0) {
                    int rr = (w >> 1) * 64 + i * 16 + quad * 4 + r;
                    smM[w & 1][rr] = mx;
                    smS[w & 1][rr] = s;
                }
            }
        }
        __syncthreads();
        if (tid < 128) {
            float ma = smM[0][tid], mb = smM[1][tid];
            float M = fmaxf(ma, mb);
            float S = smS[0][tid] * __expf(ma - M) + smS[1][tid] * __expf(mb - M);
            pp[(size_t)(m0 + tid) * NT + blockIdx.x] = make_float2(M, S);
        }
    }
}

// fp32 -> bf16 convert with zero-pad beyond n_valid. block 256, 4 elems/thread.
__global__ __launch_bounds__(256) void conv_bf16(const float* __restrict__ src,
                                                 ushort_t* __restrict__ dst,
                                                 long long n_valid, long long n_total) {
    long long base = ((long long)blockIdx.x * 256 + threadIdx.x) * 4;
    if (base >= n_total) return;
    ushort_t o[4] = {0, 0, 0, 0};
    if (base < n_valid) {
        float4 v = *(const float4*)(src + base);
        o[0] = f2bf(v.x); o[1] = f2bf(v.y); o[2] = f2bf(v.z); o[3] = f2bf(v.w);
    }
    *(ushort2*)(dst + base) = make_ushort2(o[0], o[1]);
    *(ushort2*)(dst + base + 2) = make_ushort2(o[2], o[3]);
}

// gather embedding rows directly to bf16: xe_bf[r] = bf16(emb[y[r]]).
__global__ __launch_bounds__(128) void gather_emb_bf(const float* __restrict__ emb,
                                                     const int* __restrict__ y,
                                                     ushort_t* __restrict__ xbf) {
    const int r = blockIdx.x;
    const int tok = y[r];
    const float* src = emb + (size_t)tok * 512;
    ushort_t* dst = xbf + (size_t)r * 512 + threadIdx.x * 4;
    float4 v = *(const float4*)(src + threadIdx.x * 4);
    *(ushort2*)(dst) = make_ushort2(f2bf(v.x), f2bf(v.y));
    *(ushort2*)(dst + 2) = make_ushort2(f2bf(v.z), f2bf(v.w));
}

// combine LSE partials + target logit -> per-row loss. grid = R_, block 64.
__global__ __launch_bounds__(64) void row_loss_k(const float2* __restrict__ pp,
                                                 const float* __restrict__ logit_all,
                                                 const float* __restrict__ Wv,
                                                 const float* __restrict__ bv,
                                                 const int* __restrict__ y,
                                                 float* __restrict__ rl) {
    const int r = blockIdx.x;
    const int lane = threadIdx.x;
    const int t = r / B_, b = r % B_;
    const int tgt = y[(t + 1) * B_ + b];
    float m = -1e30f;
    for (int i = lane; i < NT2; i += 64) m = fmaxf(m, pp[(size_t)r * NT2 + i].x);
    m = wmax(m); m = __shfl(m, 0);
    float s = 0;
    for (int i = lane; i < NT2; i += 64) {
        float2 p = pp[(size_t)r * NT2 + i];
        s += p.y * __expf(p.x - m);
    }
    s = wred(s);
    float d = 0;
    for (int k = lane; k < E_; k += 64) d += logit_all[(size_t)r * E_ + k] * Wv[(size_t)tgt * E_ + k];
    d = wred(d);
    if (lane == 0) {
        float lse = m + logf(s);
        rl[r] = (tgt != 0) ? (lse - (d + bv[tgt])) : 0.0f;
    }
}

__global__ __launch_bounds__(256) void sum_k(const float* __restrict__ rl, float* __restrict__ out) {
    float s = 0;
    for (int i = threadIdx.x; i < R_; i += 256) s += rl[i];
    __shared__ float red[4];
    s = wred(s);
    if ((threadIdx.x & 63) == 0) red[threadIdx.x >> 6] = s;
    __syncthreads();
    if (threadIdx.x == 0) out[0] = red[0] + red[1] + red[2] + red[3];
}

extern "C" void kernel_launch(void* const* d_in, const int* in_sizes, int n_in,
                              void* d_out, int out_size, void* d_ws, size_t ws_size,
                              hipStream_t stream) {
    const int*   y     = (const int*)d_in[0];
    const float* ctx   = (const float*)d_in[1];
    const float* emb   = (const float*)d_in[2];
    const float* W_ih0 = (const float*)d_in[3];
    const float* W_hh0 = (const float*)d_in[4];
    const float* b_ih0 = (const float*)d_in[5];
    const float* b_hh0 = (const float*)d_in[6];
    const float* W_ih1 = (const float*)d_in[7];
    const float* W_hh1 = (const float*)d_in[8];
    const float* b_ih1 = (const float*)d_in[9];
    const float* b_hh1 = (const float*)d_in[10];
    const float* W_c2c = (const float*)d_in[11];
    const float* W_h2c = (const float*)d_in[12];
    const float* w_mlp = (const float*)d_in[13];
    const float* W_h2o = (const float*)d_in[14];
    const float* b_h2o = (const float*)d_in[15];
    const float* W_o2p = (const float*)d_in[16];
    const float* b_o2p = (const float*)d_in[17];
    float* out = (float*)d_out;

    float* ws = (float*)d_ws;
    float* ctx_p      = ws; ws += (size_t)S_ * B_ * C_;                  // 4,194,304
    ushort_t* ctxp_bf = (ushort_t*)ws; ws += (size_t)S_ * B_ * C_ / 2;   // 2,097,152
    ushort_t* ctx_bf  = (ushort_t*)ws; ws += (size_t)S_ * B_ * C_ / 2;   // 2,097,152
    ushort_t* xe_bf   = (ushort_t*)ws; ws += (size_t)R_ * E_ / 2;        // 1,622,016
    float* P          = ws; ws += (size_t)6 * 64 * 3072;                 // 1,179,648
    float* Ph         = ws; ws += (size_t)4 * 64 * 512;                  // 131,072
    float* h1f        = ws; ws += (size_t)B_ * H_;                       // 65,536
    ushort_t* h1bf    = (ushort_t*)ws; ws += (size_t)B_ * H_ / 2;        // 32,768
    float* zf         = ws; ws += (size_t)B_ * C_;                       // 32,768
    ushort_t* zbf     = (ushort_t*)ws; ws += (size_t)B_ * C_ / 2;        // 16,384
    float* h2_all     = ws; ws += (size_t)R_ * H_;                       // 6,488,064
    ushort_t* h2_bf   = (ushort_t*)ws; ws += (size_t)MP_ * H_ / 2;       // 3,276,800
    float* logit_all  = ws; ws += (size_t)MP_ * E_;                      // 3,276,800
    ushort_t* lg_bf   = (ushort_t*)ws; ws += (size_t)MP_ * E_ / 2;       // 1,638,400
    ushort_t* Wih0_bf = (ushort_t*)ws; ws += (size_t)3 * H_ * E_ / 2;    // 786,432
    ushort_t* Whh0_bf = (ushort_t*)ws; ws += (size_t)3 * H_ * H_ / 2;    // 1,572,864
    ushort_t* Wih1_bf = (ushort_t*)ws; ws += (size_t)3 * H_ * C_ / 2;    // 786,432
    ushort_t* Whh1_bf = (ushort_t*)ws; ws += (size_t)3 * H_ * H_ / 2;    // 1,572,864
    ushort_t* Wh2c_bf = (ushort_t*)ws; ws += (size_t)C_ * H_ / 2;        // 262,144
    ushort_t* Wc2c_bf = (ushort_t*)ws; ws += (size_t)C_ * C_ / 2;        // 131,072
    ushort_t* Wh2o_bf = (ushort_t*)ws; ws += (size_t)E_ * H_ / 2;        // 262,144
    ushort_t* Wo2p_bf = (ushort_t*)ws; ws += (size_t)V_ * E_ / 2;        // 8,192,000
    float2* pp        = (float2*)ws; ws += (size_t)MP_ * NT2 * 2;        // 3,200,000
    float* rl         = ws; ws += R_;

    #define CONVGRID(n) dim3((unsigned)(((n) / 4 + 255) / 256))

    // ---- batched precompute (all bf16 staging) ----
    conv_bf16<<<CONVGRID((long long)S_ * B_ * C_), 256, 0, stream>>>(ctx, ctx_bf, (long long)S_ * B_ * C_, (long long)S_ * B_ * C_);
    conv_bf16<<<CONVGRID((long long)C_ * C_), 256, 0, stream>>>(W_c2c, Wc2c_bf, (long long)C_ * C_, (long long)C_ * C_);
    // ctx_p = ctx @ W_c2c^T  (bf16 MFMA, plain fp32 store)
    mfma_nt<0><<<dim3(C_ / 128, (S_ * B_) / 128), 256, 0, stream>>>(ctx_bf, Wc2c_bf, nullptr,
                                                                    ctx_p, nullptr, nullptr, C_, C_, 0);
    conv_bf16<<<CONVGRID((long long)S_ * B_ * C_), 256, 0, stream>>>(ctx_p, ctxp_bf, (long long)S_ * B_ * C_, (long long)S_ * B_ * C_);
    gather_emb_bf<<<R_, 128, 0, stream>>>(emb, y, xe_bf);
    conv_bf16<<<CONVGRID((long long)3 * H_ * E_), 256, 0, stream>>>(W_ih0, Wih0_bf, (long long)3 * H_ * E_, (long long)3 * H_ * E_);
    conv_bf16<<<CONVGRID((long long)3 * H_ * H_), 256, 0, stream>>>(W_hh0, Whh0_bf, (long long)3 * H_ * H_, (long long)3 * H_ * H_);
    conv_bf16<<<CONVGRID((long long)3 * H_ * C_), 256, 0, stream>>>(W_ih1, Wih1_bf, (long long)3 * H_ * C_, (long long)3 * H_ * C_);
    conv_bf16<<<CONVGRID((long long)3 * H_ * H_), 256, 0, stream>>>(W_hh1, Whh1_bf, (long long)3 * H_ * H_, (long long)3 * H_ * H_);
    conv_bf16<<<CONVGRID((long long)C_ * H_), 256, 0, stream>>>(W_h2c, Wh2c_bf, (long long)C_ * H_, (long long)C_ * H_);
    conv_bf16<<<CONVGRID((long long)E_ * H_), 256, 0, stream>>>(W_h2o, Wh2o_bf, (long long)E_ * H_, (long long)E_ * H_);
    conv_bf16<<<CONVGRID((long long)V_ * E_), 256, 0, stream>>>(W_o2p, Wo2p_bf, (long long)V_ * E_, (long long)V_ * E_);
    // zero the h2_bf pad rows (R_..MP_) once; never written by the loop
    conv_bf16<<<CONVGRID((long long)(MP_ - R_) * H_), 256, 0, stream>>>((const float*)d_ws, h2_bf + (size_t)R_ * H_,
                                                                        0LL, (long long)(MP_ - R_) * H_);

    // ---- sequential decode loop: 6 light dispatches per step ----
    for (int t = 0; t < TS_; ++t) {
        const ushort_t* hprev_bf = t ? h2_bf + (size_t)(t - 1) * B_ * H_ : nullptr;
        const float*    hprev_f  = t ? h2_all + (size_t)(t - 1) * B_ * H_ : nullptr;
        // GRU0: x-part (K=512, 2 slices) + h-part (K=1024, 4 slices)
        mfma_partial<<<dim3(48, 6), 256, 0, stream>>>(xe_bf + (size_t)t * B_ * E_, E_, Wih0_bf,
                                                      hprev_bf, H_, Whh0_bf, 2, P, 3072);
        gru_gate<<<256, 256, 0, stream>>>(P, b_ih0, b_hh0, hprev_f, h1f, h1bf);
        // hid = h1 @ W_h2c^T  (K=1024, 4 slices)
        mfma_partial<<<dim3(8, 4), 256, 0, stream>>>(h1bf, H_, Wh2c_bf,
                                                     nullptr, H_, nullptr, 4, Ph, C_);
        // attention -> z (fp32 + bf16)
        attn_step<<<B_, 256, 0, stream>>>(ctxp_bf, ctx_bf, Ph, w_mlp, zf, zbf);
        // GRU1: x-part = z (K=512), h-part = h1 (K=1024)
        mfma_partial<<<dim3(48, 6), 256, 0, stream>>>(zbf, C_, Wih1_bf,
                                                      h1bf, H_, Whh1_bf, 2, P, 3072);
        gru_gate<<<256, 256, 0, stream>>>(P, b_ih1, b_hh1, h1f,
                                          h2_all + (size_t)t * B_ * H_, h2_bf + (size_t)t * B_ * H_);
    }

    // ---- batched tail (bf16 MFMA; h2_bf already written by the loop) ----
    mfma_nt<1><<<dim3(E_ / 128, MP_ / 128), 256, 0, stream>>>(h2_bf, Wh2o_bf, b_h2o,
                                                              logit_all, lg_bf, nullptr, E_, H_, 0);
    mfma_nt<2><<<dim3(V_ / 128, MP_ / 128), 256, 0, stream>>>(lg_bf, Wo2p_bf, b_o2p,
                                                              nullptr, nullptr, pp, V_, E_, NT2);
    row_loss_k<<<R_, 64, 0, stream>>>(pp, logit_all, W_o2p, b_o2p, y, rl);
    sum_k<<<1, 256, 0, stream>>>(rl, out);
}